// Round 2
// baseline (6906.536 us; speedup 1.0000x reference)
//
#include <hip/hip_runtime.h>
#include <math.h>

// Problem constants (from setup_inputs): B=4, H=384, W=1280, NUM=8, IDX_REF=4
static constexpr int B_ = 4;
static constexpr int H_ = 384;
static constexpr int W_ = 1280;
static constexpr int HW_ = H_ * W_;

// ---------------------------------------------------------------------------
// Kernel 1: guidance band = [normal(3), left(3), right(3), warp(right)-left(3)]
// guid layout: (g, 12, rows, W), covering global rows [y0g, y0g+rows)
// ---------------------------------------------------------------------------
__global__ __launch_bounds__(256) void guidance_band(
    const float* __restrict__ disp, const float* __restrict__ normal,
    const float* __restrict__ left, const float* __restrict__ right,
    float* __restrict__ guid, int b0, int g, int y0g, int rows)
{
  int idx = blockIdx.x * 256 + threadIdx.x;
  if (idx >= g * rows * W_) return;
  int x = idx % W_;
  int t = idx / W_;
  int yr = t % rows;
  int gi = t / rows;
  int y = y0g + yr;
  int b = b0 + gi;
  int p = y * W_ + x;

  float d = disp[(size_t)b * HW_ + p];
  float xs = (float)x - d;
  float x0f = floorf(xs);
  int x0 = (int)x0f;
  float w1 = xs - x0f;
  int xi0 = x0, xi1 = x0 + 1;
  float v0 = (xi0 >= 0 && xi0 < W_) ? 1.f : 0.f;
  float v1 = (xi1 >= 0 && xi1 < W_) ? 1.f : 0.f;
  int xc0 = min(max(xi0, 0), W_ - 1);
  int xc1 = min(max(xi1, 0), W_ - 1);
  float w0f = (1.f - w1) * v0;
  float w1f = w1 * v1;

#pragma unroll
  for (int c = 0; c < 3; c++) {
    const float* rrow = right + (size_t)(b * 3 + c) * HW_ + (size_t)y * W_;
    float l = left[(size_t)(b * 3 + c) * HW_ + p];
    float n = normal[(size_t)(b * 3 + c) * HW_ + p];
    float r = rrow[x];
    float warped = w0f * rrow[xc0] + w1f * rrow[xc1];
    size_t base = ((size_t)gi * 12) * rows * W_ + (size_t)yr * W_ + x;
    size_t cs = (size_t)rows * W_;
    guid[base + (size_t)c * cs]       = n;
    guid[base + (size_t)(3 + c) * cs] = l;
    guid[base + (size_t)(6 + c) * cs] = r;
    guid[base + (size_t)(9 + c) * cs] = warped - l;
  }
}

// ---------------------------------------------------------------------------
// Direct 3x3 conv on a row band, pad=1 (at true image borders), optional
// fused BN+ReLU. in layout (g, C_IN, in_rows, W) covering global rows
// [in_y0, in_y0+in_rows); out layout (g, C_OUT, out_rows, W) covering
// [out_y0, out_y0+out_rows). 16x16 output tile / 256-thread block; input
// channels staged in LDS in chunks of <=32; per-thread register accumulators
// over all output channels (3x3 window read once per c_in, reused C_OUT times).
// ---------------------------------------------------------------------------
template <int C_IN, int C_OUT, bool BNRELU>
__global__ __launch_bounds__(256) void conv3x3_band(
    const float* __restrict__ in, const float* __restrict__ wgt,
    const float* __restrict__ bn_g, const float* __restrict__ bn_b,
    const float* __restrict__ bn_m, const float* __restrict__ bn_v,
    float* __restrict__ out,
    int in_y0, int in_rows, int out_y0, int out_rows)
{
  constexpr int TX = 16, TY = 16;
  constexpr int CHUNK = (C_IN < 32) ? C_IN : 32;
  static_assert(C_IN % CHUNK == 0, "chunking");
  constexpr int LH = TY + 2, LW = TX + 2;   // 18x18 logical tile
  constexpr int LWP = LW + 1;               // padded row stride (19)

  __shared__ float smem[CHUNK][LH][LWP];

  const int tilesX = W_ / TX;                      // 80
  const int tilesY = (out_rows + TY - 1) / TY;
  int t = blockIdx.x;
  int txi = t % tilesX; t /= tilesX;
  int tyi = t % tilesY;
  int gi  = t / tilesY;
  const int x0  = txi * TX;
  const int oy0 = out_y0 + tyi * TY;               // global row of tile top

  const int tid = threadIdx.x;
  const int lx = tid % TX;
  const int ly = tid / TX;

  float acc[C_OUT];
#pragma unroll
  for (int co = 0; co < C_OUT; co++) acc[co] = 0.f;

  for (int c0 = 0; c0 < C_IN; c0 += CHUNK) {
    for (int i = tid; i < CHUNK * LH * LW; i += 256) {
      int c = i / (LH * LW);
      int r = i % (LH * LW);
      int yy = r / LW;
      int xx = r % LW;
      int gy = oy0 + yy - 1;            // global image row
      int gx = x0 + xx - 1;
      int by = gy - in_y0;              // row within band buffer
      float val = 0.f;
      if (gy >= 0 && gy < H_ && gx >= 0 && gx < W_ && by >= 0 && by < in_rows)
        val = in[((size_t)(gi * C_IN + c0 + c) * in_rows + by) * W_ + gx];
      smem[c][yy][xx] = val;
    }
    __syncthreads();

    for (int c = 0; c < CHUNK; c++) {
      float i00 = smem[c][ly + 0][lx + 0];
      float i01 = smem[c][ly + 0][lx + 1];
      float i02 = smem[c][ly + 0][lx + 2];
      float i10 = smem[c][ly + 1][lx + 0];
      float i11 = smem[c][ly + 1][lx + 1];
      float i12 = smem[c][ly + 1][lx + 2];
      float i20 = smem[c][ly + 2][lx + 0];
      float i21 = smem[c][ly + 2][lx + 1];
      float i22 = smem[c][ly + 2][lx + 2];
      const int ci = c0 + c;
#pragma unroll
      for (int co = 0; co < C_OUT; co++) {
        const float* wp = wgt + ((size_t)co * C_IN + ci) * 9;
        float a = acc[co];
        a = fmaf(i00, wp[0], a);
        a = fmaf(i01, wp[1], a);
        a = fmaf(i02, wp[2], a);
        a = fmaf(i10, wp[3], a);
        a = fmaf(i11, wp[4], a);
        a = fmaf(i12, wp[5], a);
        a = fmaf(i20, wp[6], a);
        a = fmaf(i21, wp[7], a);
        a = fmaf(i22, wp[8], a);
        acc[co] = a;
      }
    }
    __syncthreads();
  }

  const int oy = oy0 + ly;              // global output row
  if (oy >= out_y0 + out_rows) return;  // partial last tile
  const int ox = x0 + lx;
#pragma unroll
  for (int co = 0; co < C_OUT; co++) {
    float r = acc[co];
    if constexpr (BNRELU) {
      float s = bn_g[co] * rsqrtf(bn_v[co] + 1e-5f);
      r = r * s + (bn_b[co] - bn_m[co] * s);
      r = fmaxf(r, 0.f);
    }
    out[((size_t)(gi * C_OUT + co) * out_rows + (oy - out_y0)) * W_ + ox] = r;
  }
}

// ---------------------------------------------------------------------------
// Fused propagation epilogue over a band.
// oa layout (g, 24, rows, W): [o1(8)=dy, o2(8)=dx, aff_raw(8)]
// ---------------------------------------------------------------------------
__device__ __forceinline__ float bilin1(const float* __restrict__ img,
                                        float ys, float xs)
{
  float y0f = floorf(ys), x0f = floorf(xs);
  int y0 = (int)y0f, x0 = (int)x0f;
  float wy1 = ys - y0f, wx1 = xs - x0f;
  float wy0 = 1.f - wy1, wx0 = 1.f - wx1;
  int y1 = y0 + 1, x1 = x0 + 1;
  float vy0 = (y0 >= 0 && y0 < H_) ? 1.f : 0.f;
  float vy1 = (y1 >= 0 && y1 < H_) ? 1.f : 0.f;
  float vx0 = (x0 >= 0 && x0 < W_) ? 1.f : 0.f;
  float vx1 = (x1 >= 0 && x1 < W_) ? 1.f : 0.f;
  int yc0 = min(max(y0, 0), H_ - 1), yc1 = min(max(y1, 0), H_ - 1);
  int xc0 = min(max(x0, 0), W_ - 1), xc1 = min(max(x1, 0), W_ - 1);
  const float* r0 = img + (size_t)yc0 * W_;
  const float* r1 = img + (size_t)yc1 * W_;
  float v00 = r0[xc0], v01 = r0[xc1], v10 = r1[xc0], v11 = r1[xc1];
  return (wy0 * vy0) * ((wx0 * vx0) * v00 + (wx1 * vx1) * v01) +
         (wy1 * vy1) * ((wx0 * vx0) * v10 + (wx1 * vx1) * v11);
}

__global__ __launch_bounds__(256) void final_band(
    const float* __restrict__ oa, const float* __restrict__ conf,
    const float* __restrict__ disp, const float* __restrict__ asc,
    float* __restrict__ out, int b0, int g, int y0g, int rows)
{
  int idx = blockIdx.x * 256 + threadIdx.x;
  if (idx >= g * rows * W_) return;
  int x = idx % W_;
  int t = idx / W_;
  int yr = t % rows;
  int gi = t / rows;
  int y = y0g + yr;
  int b = b0 + gi;
  int p = y * W_ + x;

  const float scale = 1.f / (asc[0] + 1e-8f);
  const float* cimg = conf + (size_t)b * HW_;
  const float* dimg = disp + (size_t)b * HW_;
  const float* oab = oa + (size_t)gi * 24 * rows * W_;
  const size_t cs = (size_t)rows * W_;
  const size_t q = (size_t)yr * W_ + x;

  float offy[8], offx[8], a[8];
#pragma unroll
  for (int k = 0; k < 8; k++) {
    offy[k] = oab[(size_t)k * cs + q];
    offx[k] = oab[(size_t)(8 + k) * cs + q];
    float ar = oab[(size_t)(16 + k) * cs + q];
    float ca = bilin1(cimg, (float)y + offy[k], (float)x + offx[k]);
    a[k] = tanhf(ar) * scale * ca;
  }

  float s = 1e-4f;
#pragma unroll
  for (int k = 0; k < 8; k++) s += fabsf(a[k]);
  s = fmaxf(s, 1.f);
  float inv = 1.f / s;
  float suma = 0.f;
#pragma unroll
  for (int k = 0; k < 8; k++) { a[k] *= inv; suma += a[k]; }
  float aref = 1.f - suma;

  float inter = 0.f;
#pragma unroll
  for (int k9 = 0; k9 < 9; k9++) {
    float oy, ox, w;
    if (k9 < 4)       { oy = offy[k9];     ox = offx[k9];     w = a[k9]; }
    else if (k9 == 4) { oy = 0.f;          ox = 0.f;          w = aref;  }
    else              { oy = offy[k9 - 1]; ox = offx[k9 - 1]; w = a[k9 - 1]; }
    float ky = (float)(k9 / 3) - 1.f;
    float kx = (float)(k9 % 3) - 1.f;
    inter += w * bilin1(dimg, (float)y + ky + oy, (float)x + kx + ox);
  }
  inter = fmaxf(inter, 0.f);
  float cd = dimg[p];
  out[(size_t)b * HW_ + p] = fmaxf(0.7f * cd + 0.3f * inter, 0.f);
}

// ---------------------------------------------------------------------------
extern "C" void kernel_launch(void* const* d_in, const int* in_sizes, int n_in,
                              void* d_out, int out_size, void* d_ws, size_t ws_size,
                              hipStream_t stream)
{
  const float* disp   = (const float*)d_in[0];
  const float* normal = (const float*)d_in[1];
  const float* left   = (const float*)d_in[2];
  const float* right  = (const float*)d_in[3];
  const float* conf   = (const float*)d_in[4];
  const float* w1     = (const float*)d_in[5];
  const float* g1     = (const float*)d_in[6];
  const float* b1     = (const float*)d_in[7];
  const float* v1b    = (const float*)d_in[8];   // bn1_m
  const float* v1v    = (const float*)d_in[9];   // bn1_v
  const float* w2     = (const float*)d_in[10];
  const float* g2     = (const float*)d_in[11];
  const float* b2     = (const float*)d_in[12];
  const float* m2     = (const float*)d_in[13];
  const float* v2     = (const float*)d_in[14];
  const float* w3     = (const float*)d_in[15];
  const float* asc    = (const float*)d_in[16];
  float* out = (float*)d_out;

  // Pick the largest (batch-group g, band height bh) whose fp32 band buffers
  // fit in ws_size. Buffer rows (upper bound, interior band):
  //   guid: bh+6 (12 ch), x1: bh+4 (32 ch), x2: bh+2 (64 ch), oa: bh (24 ch)
  struct Cfg { int g, bh; };
  const Cfg cfgs[] = {{4, 384}, {4, 192}, {4, 96}, {4, 48}, {2, 48},
                      {1, 48}, {1, 24}, {1, 12}, {1, 8}, {1, 4}};
  int G = 1, BH = 4;
  for (const Cfg& c : cfgs) {
    size_t rows = (size_t)12 * (c.bh + 6) + (size_t)32 * (c.bh + 4) +
                  (size_t)64 * (c.bh + 2) + (size_t)24 * c.bh;
    size_t need = (size_t)c.g * rows * W_ * sizeof(float);
    if (need <= ws_size) { G = c.g; BH = c.bh; break; }
  }

  float* ws = (float*)d_ws;
  float* guid_buf = ws;
  float* x1_buf   = guid_buf + (size_t)G * 12 * (BH + 6) * W_;
  float* x2_buf   = x1_buf   + (size_t)G * 32 * (BH + 4) * W_;
  float* oa_buf   = x2_buf   + (size_t)G * 64 * (BH + 2) * W_;

  const int tilesX = W_ / 16;  // 80

  for (int b0 = 0; b0 < B_; b0 += G) {
    for (int y0 = 0; y0 < H_; y0 += BH) {
      const int rows_out = min(BH, H_ - y0);
      // halo row ranges (clamped to image)
      const int y_x2_0 = max(y0 - 1, 0);
      const int y_x2_1 = min(y0 + rows_out + 1, H_);
      const int rows_x2 = y_x2_1 - y_x2_0;
      const int y_x1_0 = max(y0 - 2, 0);
      const int y_x1_1 = min(y0 + rows_out + 2, H_);
      const int rows_x1 = y_x1_1 - y_x1_0;
      const int y_g_0 = max(y0 - 3, 0);
      const int y_g_1 = min(y0 + rows_out + 3, H_);
      const int rows_g = y_g_1 - y_g_0;

      {
        int n = G * rows_g * W_;
        guidance_band<<<(n + 255) / 256, 256, 0, stream>>>(
            disp, normal, left, right, guid_buf, b0, G, y_g_0, rows_g);
      }
      {
        int grid = tilesX * ((rows_x1 + 15) / 16) * G;
        conv3x3_band<12, 32, true><<<grid, 256, 0, stream>>>(
            guid_buf, w1, g1, b1, v1b, v1v, x1_buf,
            y_g_0, rows_g, y_x1_0, rows_x1);
      }
      {
        int grid = tilesX * ((rows_x2 + 15) / 16) * G;
        conv3x3_band<32, 64, true><<<grid, 256, 0, stream>>>(
            x1_buf, w2, g2, b2, m2, v2, x2_buf,
            y_x1_0, rows_x1, y_x2_0, rows_x2);
      }
      {
        int grid = tilesX * ((rows_out + 15) / 16) * G;
        conv3x3_band<64, 24, false><<<grid, 256, 0, stream>>>(
            x2_buf, w3, nullptr, nullptr, nullptr, nullptr, oa_buf,
            y_x2_0, rows_x2, y0, rows_out);
      }
      {
        int n = G * rows_out * W_;
        final_band<<<(n + 255) / 256, 256, 0, stream>>>(
            oa_buf, conf, disp, asc, out, b0, G, y0, rows_out);
      }
    }
  }
}

// Round 3
// 4125.113 us; speedup vs baseline: 1.6743x; 1.6743x over previous
//
#include <hip/hip_runtime.h>
#include <math.h>

// Problem constants (from setup_inputs): B=4, H=384, W=1280, NUM=8, IDX_REF=4
static constexpr int B_ = 4;
static constexpr int H_ = 384;
static constexpr int W_ = 1280;
static constexpr int HW_ = H_ * W_;

// ---------------------------------------------------------------------------
// Kernel 1: guidance band = [normal(3), left(3), right(3), warp(right)-left(3)]
// guid layout: (g, 12, rows, W), covering global rows [y0g, y0g+rows)
// ---------------------------------------------------------------------------
__global__ __launch_bounds__(256) void guidance_band(
    const float* __restrict__ disp, const float* __restrict__ normal,
    const float* __restrict__ left, const float* __restrict__ right,
    float* __restrict__ guid, int b0, int g, int y0g, int rows)
{
  int idx = blockIdx.x * 256 + threadIdx.x;
  if (idx >= g * rows * W_) return;
  int x = idx % W_;
  int t = idx / W_;
  int yr = t % rows;
  int gi = t / rows;
  int y = y0g + yr;
  int b = b0 + gi;
  int p = y * W_ + x;

  float d = disp[(size_t)b * HW_ + p];
  float xs = (float)x - d;
  float x0f = floorf(xs);
  int x0 = (int)x0f;
  float w1 = xs - x0f;
  int xi0 = x0, xi1 = x0 + 1;
  float v0 = (xi0 >= 0 && xi0 < W_) ? 1.f : 0.f;
  float v1 = (xi1 >= 0 && xi1 < W_) ? 1.f : 0.f;
  int xc0 = min(max(xi0, 0), W_ - 1);
  int xc1 = min(max(xi1, 0), W_ - 1);
  float w0f = (1.f - w1) * v0;
  float w1f = w1 * v1;

#pragma unroll
  for (int c = 0; c < 3; c++) {
    const float* rrow = right + (size_t)(b * 3 + c) * HW_ + (size_t)y * W_;
    float l = left[(size_t)(b * 3 + c) * HW_ + p];
    float n = normal[(size_t)(b * 3 + c) * HW_ + p];
    float r = rrow[x];
    float warped = w0f * rrow[xc0] + w1f * rrow[xc1];
    size_t base = ((size_t)gi * 12) * rows * W_ + (size_t)yr * W_ + x;
    size_t cs = (size_t)rows * W_;
    guid[base + (size_t)c * cs]       = n;
    guid[base + (size_t)(3 + c) * cs] = l;
    guid[base + (size_t)(6 + c) * cs] = r;
    guid[base + (size_t)(9 + c) * cs] = warped - l;
  }
}

// ---------------------------------------------------------------------------
// Direct 3x3 conv on a row band, pad=1 (at true image borders), optional
// fused BN+ReLU. Each block computes a 16x16 pixel tile x CO_TILE output
// channels (acc[CO_TILE] in registers -> low VGPR pressure, no AGPR shuffle).
// Input channels staged in LDS in chunks of CHUNK (<=16 -> 21.9 KB -> 7
// blocks/CU). Grid layout: tilesX * tilesY * (C_OUT/CO_TILE) * g.
// Accumulation order per output (c ascending, tap ascending) is identical to
// the previous round -> bit-identical numerics.
// ---------------------------------------------------------------------------
template <int C_IN, int C_OUT, int CO_TILE, int CHUNK, bool BNRELU>
__global__ __launch_bounds__(256) void conv3x3_band(
    const float* __restrict__ in, const float* __restrict__ wgt,
    const float* __restrict__ bn_g, const float* __restrict__ bn_b,
    const float* __restrict__ bn_m, const float* __restrict__ bn_v,
    float* __restrict__ out,
    int in_y0, int in_rows, int out_y0, int out_rows)
{
  constexpr int TX = 16, TY = 16;
  static_assert(C_IN % CHUNK == 0, "chunking");
  static_assert(C_OUT % CO_TILE == 0, "co tiling");
  constexpr int NCO = C_OUT / CO_TILE;
  constexpr int LH = TY + 2, LW = TX + 2;   // 18x18 logical tile
  constexpr int LWP = LW + 1;               // padded row stride (19)

  __shared__ float smem[CHUNK][LH][LWP];

  const int tilesX = W_ / TX;                      // 80
  const int tilesY = (out_rows + TY - 1) / TY;
  int t = blockIdx.x;
  int txi = t % tilesX; t /= tilesX;
  int tyi = t % tilesY; t /= tilesY;
  int coi = t % NCO;
  int gi  = t / NCO;
  const int x0  = txi * TX;
  const int oy0 = out_y0 + tyi * TY;               // global row of tile top
  const int co0 = coi * CO_TILE;

  const int tid = threadIdx.x;
  const int lx = tid % TX;
  const int ly = tid / TX;

  float acc[CO_TILE];
#pragma unroll
  for (int j = 0; j < CO_TILE; j++) acc[j] = 0.f;

  for (int c0 = 0; c0 < C_IN; c0 += CHUNK) {
    for (int i = tid; i < CHUNK * LH * LW; i += 256) {
      int c = i / (LH * LW);
      int r = i % (LH * LW);
      int yy = r / LW;
      int xx = r % LW;
      int gy = oy0 + yy - 1;            // global image row
      int gx = x0 + xx - 1;
      int by = gy - in_y0;              // row within band buffer
      float val = 0.f;
      if (gy >= 0 && gy < H_ && gx >= 0 && gx < W_ && by >= 0 && by < in_rows)
        val = in[((size_t)(gi * C_IN + c0 + c) * in_rows + by) * W_ + gx];
      smem[c][yy][xx] = val;
    }
    __syncthreads();

    for (int c = 0; c < CHUNK; c++) {
      float i00 = smem[c][ly + 0][lx + 0];
      float i01 = smem[c][ly + 0][lx + 1];
      float i02 = smem[c][ly + 0][lx + 2];
      float i10 = smem[c][ly + 1][lx + 0];
      float i11 = smem[c][ly + 1][lx + 1];
      float i12 = smem[c][ly + 1][lx + 2];
      float i20 = smem[c][ly + 2][lx + 0];
      float i21 = smem[c][ly + 2][lx + 1];
      float i22 = smem[c][ly + 2][lx + 2];
      const int ci = c0 + c;
#pragma unroll
      for (int j = 0; j < CO_TILE; j++) {
        const float* wp = wgt + ((size_t)(co0 + j) * C_IN + ci) * 9;
        float a = acc[j];
        a = fmaf(i00, wp[0], a);
        a = fmaf(i01, wp[1], a);
        a = fmaf(i02, wp[2], a);
        a = fmaf(i10, wp[3], a);
        a = fmaf(i11, wp[4], a);
        a = fmaf(i12, wp[5], a);
        a = fmaf(i20, wp[6], a);
        a = fmaf(i21, wp[7], a);
        a = fmaf(i22, wp[8], a);
        acc[j] = a;
      }
    }
    __syncthreads();
  }

  const int oy = oy0 + ly;              // global output row
  if (oy >= out_y0 + out_rows) return;  // partial last tile
  const int ox = x0 + lx;
#pragma unroll
  for (int j = 0; j < CO_TILE; j++) {
    float r = acc[j];
    const int co = co0 + j;
    if constexpr (BNRELU) {
      float s = bn_g[co] * rsqrtf(bn_v[co] + 1e-5f);
      r = r * s + (bn_b[co] - bn_m[co] * s);
      r = fmaxf(r, 0.f);
    }
    out[((size_t)(gi * C_OUT + co) * out_rows + (oy - out_y0)) * W_ + ox] = r;
  }
}

// ---------------------------------------------------------------------------
// Fused propagation epilogue over a band.
// oa layout (g, 24, rows, W): [o1(8)=dy, o2(8)=dx, aff_raw(8)]
// ---------------------------------------------------------------------------
__device__ __forceinline__ float bilin1(const float* __restrict__ img,
                                        float ys, float xs)
{
  float y0f = floorf(ys), x0f = floorf(xs);
  int y0 = (int)y0f, x0 = (int)x0f;
  float wy1 = ys - y0f, wx1 = xs - x0f;
  float wy0 = 1.f - wy1, wx0 = 1.f - wx1;
  int y1 = y0 + 1, x1 = x0 + 1;
  float vy0 = (y0 >= 0 && y0 < H_) ? 1.f : 0.f;
  float vy1 = (y1 >= 0 && y1 < H_) ? 1.f : 0.f;
  float vx0 = (x0 >= 0 && x0 < W_) ? 1.f : 0.f;
  float vx1 = (x1 >= 0 && x1 < W_) ? 1.f : 0.f;
  int yc0 = min(max(y0, 0), H_ - 1), yc1 = min(max(y1, 0), H_ - 1);
  int xc0 = min(max(x0, 0), W_ - 1), xc1 = min(max(x1, 0), W_ - 1);
  const float* r0 = img + (size_t)yc0 * W_;
  const float* r1 = img + (size_t)yc1 * W_;
  float v00 = r0[xc0], v01 = r0[xc1], v10 = r1[xc0], v11 = r1[xc1];
  return (wy0 * vy0) * ((wx0 * vx0) * v00 + (wx1 * vx1) * v01) +
         (wy1 * vy1) * ((wx0 * vx0) * v10 + (wx1 * vx1) * v11);
}

__global__ __launch_bounds__(256) void final_band(
    const float* __restrict__ oa, const float* __restrict__ conf,
    const float* __restrict__ disp, const float* __restrict__ asc,
    float* __restrict__ out, int b0, int g, int y0g, int rows)
{
  int idx = blockIdx.x * 256 + threadIdx.x;
  if (idx >= g * rows * W_) return;
  int x = idx % W_;
  int t = idx / W_;
  int yr = t % rows;
  int gi = t / rows;
  int y = y0g + yr;
  int b = b0 + gi;
  int p = y * W_ + x;

  const float scale = 1.f / (asc[0] + 1e-8f);
  const float* cimg = conf + (size_t)b * HW_;
  const float* dimg = disp + (size_t)b * HW_;
  const float* oab = oa + (size_t)gi * 24 * rows * W_;
  const size_t cs = (size_t)rows * W_;
  const size_t q = (size_t)yr * W_ + x;

  float offy[8], offx[8], a[8];
#pragma unroll
  for (int k = 0; k < 8; k++) {
    offy[k] = oab[(size_t)k * cs + q];
    offx[k] = oab[(size_t)(8 + k) * cs + q];
    float ar = oab[(size_t)(16 + k) * cs + q];
    float ca = bilin1(cimg, (float)y + offy[k], (float)x + offx[k]);
    a[k] = tanhf(ar) * scale * ca;
  }

  float s = 1e-4f;
#pragma unroll
  for (int k = 0; k < 8; k++) s += fabsf(a[k]);
  s = fmaxf(s, 1.f);
  float inv = 1.f / s;
  float suma = 0.f;
#pragma unroll
  for (int k = 0; k < 8; k++) { a[k] *= inv; suma += a[k]; }
  float aref = 1.f - suma;

  float inter = 0.f;
#pragma unroll
  for (int k9 = 0; k9 < 9; k9++) {
    float oy, ox, w;
    if (k9 < 4)       { oy = offy[k9];     ox = offx[k9];     w = a[k9]; }
    else if (k9 == 4) { oy = 0.f;          ox = 0.f;          w = aref;  }
    else              { oy = offy[k9 - 1]; ox = offx[k9 - 1]; w = a[k9 - 1]; }
    float ky = (float)(k9 / 3) - 1.f;
    float kx = (float)(k9 % 3) - 1.f;
    inter += w * bilin1(dimg, (float)y + ky + oy, (float)x + kx + ox);
  }
  inter = fmaxf(inter, 0.f);
  float cd = dimg[p];
  out[(size_t)b * HW_ + p] = fmaxf(0.7f * cd + 0.3f * inter, 0.f);
}

// ---------------------------------------------------------------------------
extern "C" void kernel_launch(void* const* d_in, const int* in_sizes, int n_in,
                              void* d_out, int out_size, void* d_ws, size_t ws_size,
                              hipStream_t stream)
{
  const float* disp   = (const float*)d_in[0];
  const float* normal = (const float*)d_in[1];
  const float* left   = (const float*)d_in[2];
  const float* right  = (const float*)d_in[3];
  const float* conf   = (const float*)d_in[4];
  const float* w1     = (const float*)d_in[5];
  const float* g1     = (const float*)d_in[6];
  const float* b1     = (const float*)d_in[7];
  const float* m1     = (const float*)d_in[8];
  const float* v1     = (const float*)d_in[9];
  const float* w2     = (const float*)d_in[10];
  const float* g2     = (const float*)d_in[11];
  const float* b2     = (const float*)d_in[12];
  const float* m2     = (const float*)d_in[13];
  const float* v2     = (const float*)d_in[14];
  const float* w3     = (const float*)d_in[15];
  const float* asc    = (const float*)d_in[16];
  float* out = (float*)d_out;

  // Pick the largest (batch-group g, band height bh) whose fp32 band buffers
  // fit in ws_size.
  struct Cfg { int g, bh; };
  const Cfg cfgs[] = {{4, 384}, {4, 192}, {4, 96}, {4, 48}, {2, 48},
                      {1, 48}, {1, 24}, {1, 12}, {1, 8}, {1, 4}};
  int G = 1, BH = 4;
  for (const Cfg& c : cfgs) {
    size_t rows = (size_t)12 * (c.bh + 6) + (size_t)32 * (c.bh + 4) +
                  (size_t)64 * (c.bh + 2) + (size_t)24 * c.bh;
    size_t need = (size_t)c.g * rows * W_ * sizeof(float);
    if (need <= ws_size) { G = c.g; BH = c.bh; break; }
  }

  float* ws = (float*)d_ws;
  float* guid_buf = ws;
  float* x1_buf   = guid_buf + (size_t)G * 12 * (BH + 6) * W_;
  float* x2_buf   = x1_buf   + (size_t)G * 32 * (BH + 4) * W_;
  float* oa_buf   = x2_buf   + (size_t)G * 64 * (BH + 2) * W_;

  const int tilesX = W_ / 16;  // 80

  for (int b0 = 0; b0 < B_; b0 += G) {
    for (int y0 = 0; y0 < H_; y0 += BH) {
      const int rows_out = min(BH, H_ - y0);
      const int y_x2_0 = max(y0 - 1, 0);
      const int y_x2_1 = min(y0 + rows_out + 1, H_);
      const int rows_x2 = y_x2_1 - y_x2_0;
      const int y_x1_0 = max(y0 - 2, 0);
      const int y_x1_1 = min(y0 + rows_out + 2, H_);
      const int rows_x1 = y_x1_1 - y_x1_0;
      const int y_g_0 = max(y0 - 3, 0);
      const int y_g_1 = min(y0 + rows_out + 3, H_);
      const int rows_g = y_g_1 - y_g_0;

      {
        int n = G * rows_g * W_;
        guidance_band<<<(n + 255) / 256, 256, 0, stream>>>(
            disp, normal, left, right, guid_buf, b0, G, y_g_0, rows_g);
      }
      {
        // 12 -> 32, CO_TILE=16 (2 co-blocks), CHUNK=12
        int grid = tilesX * ((rows_x1 + 15) / 16) * 2 * G;
        conv3x3_band<12, 32, 16, 12, true><<<grid, 256, 0, stream>>>(
            guid_buf, w1, g1, b1, m1, v1, x1_buf,
            y_g_0, rows_g, y_x1_0, rows_x1);
      }
      {
        // 32 -> 64, CO_TILE=16 (4 co-blocks), CHUNK=16
        int grid = tilesX * ((rows_x2 + 15) / 16) * 4 * G;
        conv3x3_band<32, 64, 16, 16, true><<<grid, 256, 0, stream>>>(
            x1_buf, w2, g2, b2, m2, v2, x2_buf,
            y_x1_0, rows_x1, y_x2_0, rows_x2);
      }
      {
        // 64 -> 24, CO_TILE=12 (2 co-blocks), CHUNK=16
        int grid = tilesX * ((rows_out + 15) / 16) * 2 * G;
        conv3x3_band<64, 24, 12, 16, false><<<grid, 256, 0, stream>>>(
            x2_buf, w3, nullptr, nullptr, nullptr, nullptr, oa_buf,
            y_x2_0, rows_x2, y0, rows_out);
      }
      {
        int n = G * rows_out * W_;
        final_band<<<(n + 255) / 256, 256, 0, stream>>>(
            oa_buf, conf, disp, asc, out, b0, G, y0, rows_out);
      }
    }
  }
}